// Round 11
// baseline (225.507 us; speedup 1.0000x reference)
//
#include <hip/hip_runtime.h>
#include <hip/hip_bf16.h>
#include <math.h>

#define D      512
#define BQ     128
#define KK     3
#define THR    0.15f
#define SSCALE 5.0f
#define SENT   0x7fffffff
#define NBLK   256
#define NSTR   (NBLK * 4)
#define NB4    (NBLK * 4)
#define IDXM   0x3FFFFu

using bf16x8 = __attribute__((ext_vector_type(8))) short;
using f32x4  = __attribute__((ext_vector_type(4))) float;

__device__ __forceinline__ unsigned short f2bf(float x) {
    unsigned u = __float_as_uint(x);
    return (unsigned short)((u + 0x7fffu + ((u >> 16) & 1u)) >> 16);
}

__device__ __forceinline__ unsigned pk2(float lo, float hi) {
    __hip_bfloat162 h = __float22bfloat162_rn(make_float2(lo, hi));
    union { __hip_bfloat162 h; unsigned u; } c; c.h = h;
    return c.u;
}

__device__ __forceinline__ bf16x8 cvt8(float4 f0, float4 f1) {
    union { unsigned u[4]; bf16x8 v; } r;
    r.u[0] = pk2(f0.x, f0.y);
    r.u[1] = pk2(f0.z, f0.w);
    r.u[2] = pk2(f1.x, f1.y);
    r.u[3] = pk2(f1.z, f1.w);
    return r.v;
}

// ordered-float: monotone u32 mapping of f32
__device__ __forceinline__ unsigned ordf(float v) {
    unsigned u = __float_as_uint(v);
    return u ^ ((unsigned)((int)u >> 31) | 0x80000000u);
}

// guarded descending insert into a 4-key list (keys pack value|~idx: tie -> lower idx wins)
__device__ __forceinline__ void insk4(unsigned key, unsigned K[4]) {
    if (key > K[3]) {
        bool b0 = key > K[0], b1 = key > K[1], b2 = key > K[2];
        unsigned k0 = K[0], k1 = K[1], k2 = K[2];
        K[0] = b0 ? key : k0;
        K[1] = b0 ? k0 : (b1 ? key : k1);
        K[2] = b1 ? k1 : (b2 ? key : k2);
        K[3] = b2 ? k2 : key;
    }
}

__device__ __forceinline__ void insk8(unsigned key, unsigned* K) {
    if (key <= K[7]) return;
    #pragma unroll
    for (int k = 0; k < 8; ++k) {
        if (key > K[k]) {
            #pragma unroll
            for (int m = 7; m > k; --m) K[m] = K[m-1];
            K[k] = key;
            return;
        }
    }
}

// exact float top-4 with (value desc, idx asc) tie rule — matches jax.lax.top_k
template<int K>
__device__ __forceinline__ void insK(float v, int c, float* V, int* C) {
    #pragma unroll
    for (int k = 0; k < K; ++k) {
        if (v > V[k] || (v == V[k] && c < C[k])) {
            #pragma unroll
            for (int m = K - 1; m > k; --m) { V[m] = V[m-1]; C[m] = C[m-1]; }
            V[k] = v; C[k] = c;
            return;
        }
    }
}

// ---------------- kernel 1: normalize i_feats + query bf16 fragment image ----------------
// apre element (q, c, g) at index g*2048 + c*128 + q  (16B each): bf16 of
// ihat[q][k], k = c*32 + g*8 .. +8
__global__ void prep_kernel(const float* __restrict__ x, float* __restrict__ ihat,
                            uint4* __restrict__ apre) {
    int r = blockIdx.x;
    int l = threadIdx.x;             // 0..63, owns k = l*8 .. +8  (c = l>>2, g = l&3)
    const float4* row = (const float4*)(x + (size_t)r * D);
    float4 v0 = row[l * 2 + 0];
    float4 v1 = row[l * 2 + 1];
    float s = v0.x*v0.x + v0.y*v0.y + v0.z*v0.z + v0.w*v0.w
            + v1.x*v1.x + v1.y*v1.y + v1.z*v1.z + v1.w*v1.w;
    #pragma unroll
    for (int off = 32; off > 0; off >>= 1) s += __shfl_xor(s, off);
    float inv = 1.0f / sqrtf(s);
    float a0 = v0.x*inv, a1 = v0.y*inv, a2 = v0.z*inv, a3 = v0.w*inv;
    float a4 = v1.x*inv, a5 = v1.y*inv, a6 = v1.z*inv, a7 = v1.w*inv;
    float4* orow = (float4*)(ihat + (size_t)r * D);
    orow[l*2+0] = make_float4(a0, a1, a2, a3);
    orow[l*2+1] = make_float4(a4, a5, a6, a7);
    uint4 p;
    p.x = f2bf(a0) | ((unsigned)f2bf(a1) << 16);
    p.y = f2bf(a2) | ((unsigned)f2bf(a3) << 16);
    p.z = f2bf(a4) | ((unsigned)f2bf(a5) << 16);
    p.w = f2bf(a6) | ((unsigned)f2bf(a7) << 16);
    apre[((l & 3) << 11) + ((l >> 2) << 7) + r] = p;
}

// ---------------- kernel 2: streaming MFMA sim + packed-key top-4, wave-paired ---------
// 8 waves = 4 pairs. Pair pr streams tile t = blockIdx*4+pr (+= NSTR); the two waves
// of a pair (h = wid&1) each cover 64 of the 128 queries (4 MFMA frags). Per-wave
// state ~95 VGPR < 128 cap (no spill; R9 verified).
// R11: depth-4/crossover-12 rotation reverted from R10's broken depth-6 (16%6!=0 —
// pre[] phase shifted by 4 every tile, MFMA consumed permuted k-slices).
// NEW: sched_barrier(0) between each chunk's prefetch-issue and its compute pins the
// 4-chunk prefetch distance in emitted ISA (hypothesis: MI scheduler was sinking
// loads to uses under the 128-VGPR cap -> effective depth ~1 -> 2.2 TB/s plateau).
__global__ __launch_bounds__(512)
void sim_topk(const uint4* __restrict__ apre, const float* __restrict__ img,
              int N, int ntiles, int nit, unsigned* __restrict__ pk)
{
    extern __shared__ __align__(16) unsigned char Bs[];   // 131072 B
    const int tid  = threadIdx.x;
    const int lane = tid & 63;
    const int wid  = tid >> 6;
    const int lr   = lane & 15;
    const int kg   = lane >> 4;
    const int h    = wid & 1;
    const int pr   = wid >> 1;

    // stage query frags -> LDS (one-time): element (q,c,g) at c*8192 + g*2048 + q*16
    #pragma unroll
    for (int j = 0; j < 16; ++j) {
        int s = tid + j * 512;                 // 0..8191
        uint4 p = apre[s];
        int addr = ((s >> 7) & 15) * 8192 + (s >> 11) * 2048 + (s & 127) * 16;
        *(uint4*)(Bs + addr) = p;
    }
    __syncthreads();

    // frag(nf, c) = Bs + c*8192 + lane_off + nf*256 ; q = h*64 + nf*16 + lr
    const int lane_off = kg * 2048 + h * 1024 + lr * 16;

    // per-lane running top-4 keys for 4 queries
    unsigned keys[4][4];
    #pragma unroll
    for (int nf = 0; nf < 4; ++nf)
        #pragma unroll
        for (int s = 0; s < 4; ++s) keys[nf][s] = 0u;

    const int sid = blockIdx.x * 4 + pr;
    int t = sid;
    const float* gp;
    {
        int row = t * 16 + lr;
        if (row >= N) row = N - 1;
        gp = img + (size_t)row * D + kg * 8;
    }

    float4 pre[4][2];
    if (t < ntiles) {
        #pragma unroll
        for (int c = 0; c < 4; ++c) {
            pre[c][0] = *(const float4*)(gp + c * 32);
            pre[c][1] = *(const float4*)(gp + c * 32 + 4);
        }
    }

#define CHUNK(c) do {                                                          \
        float4 f0_ = pre[(c) & 3][0], f1_ = pre[(c) & 3][1];                   \
        if ((c) < 12) {                                                        \
            pre[(c) & 3][0] = *(const float4*)(gp + ((c) + 4) * 32);           \
            pre[(c) & 3][1] = *(const float4*)(gp + ((c) + 4) * 32 + 4);       \
        } else {                                                               \
            pre[(c) & 3][0] = *(const float4*)(gpn + ((c) - 12) * 32);         \
            pre[(c) & 3][1] = *(const float4*)(gpn + ((c) - 12) * 32 + 4);     \
        }                                                                      \
        __builtin_amdgcn_sched_barrier(0);  /* loads stay issued HERE */       \
        sq += f0_.x*f0_.x + f0_.y*f0_.y + f0_.z*f0_.z + f0_.w*f0_.w            \
            + f1_.x*f1_.x + f1_.y*f1_.y + f1_.z*f1_.z + f1_.w*f1_.w;           \
        bf16x8 a_ = cvt8(f0_, f1_);                                            \
        const unsigned char* bp_ = Bs + (c) * 8192 + lane_off;                 \
        _Pragma("unroll")                                                      \
        for (int nf_ = 0; nf_ < 4; ++nf_) {                                    \
            bf16x8 b_ = *(const bf16x8*)(bp_ + nf_ * 256);                     \
            acc[nf_] = __builtin_amdgcn_mfma_f32_16x16x32_bf16(a_, b_, acc[nf_], 0, 0, 0); \
        }                                                                      \
    } while (0)

    for (int it = 0; it < nit; ++it) {
        int tn = t + NSTR;
        if (t < ntiles) {
            const float* gpn;
            {
                int tt = (tn < ntiles) ? tn : t;
                int row = tt * 16 + lr;
                if (row >= N) row = N - 1;
                gpn = img + (size_t)row * D + kg * 8;
            }
            f32x4 acc[4];
            #pragma unroll
            for (int nf = 0; nf < 4; ++nf) acc[nf] = (f32x4){0.f, 0.f, 0.f, 0.f};
            float sq = 0.f;

            CHUNK(0);  CHUNK(1);  CHUNK(2);  CHUNK(3);
            CHUNK(4);  CHUNK(5);  CHUNK(6);  CHUNK(7);
            CHUNK(8);  CHUNK(9);  CHUNK(10); CHUNK(11);
            CHUNK(12); CHUNK(13); CHUNK(14); CHUNK(15);

            // row norms: lane's sq covers its row's kg-slices; butterfly over kg lanes
            float s2 = sq;
            s2 += __shfl_xor(s2, 16);
            s2 += __shfl_xor(s2, 32);
            float rnorm = s2 > 0.f ? rsqrtf(s2) : 0.f;

            const int ib = t * 16 + kg * 4;
            #pragma unroll
            for (int g = 0; g < 4; ++g) {
                int idx = ib + g;
                bool ok = idx < N;
                unsigned ic = (unsigned)idx ^ IDXM;
                float r = __shfl(rnorm, kg * 4 + g);
                #pragma unroll
                for (int nf = 0; nf < 4; ++nf) {
                    unsigned o   = ordf(acc[nf][g] * r);
                    unsigned key = ok ? ((o & 0xFFFC0000u) | ic) : 0u;
                    insk4(key, keys[nf]);
                }
            }
            gp = gpn;
        }
        t = tn;
        if (it & 1) __builtin_amdgcn_s_barrier();   // rendezvous every 2 tiles: bounds pair drift
    }
#undef CHUNK

    // merge across the 4 kg lane-groups (same query lives in lanes lr, lr+16, lr+32, lr+48)
    #pragma unroll
    for (int nf = 0; nf < 4; ++nf) {
        #pragma unroll
        for (int st = 0; st < 2; ++st) {
            const int off = st ? 32 : 16;
            unsigned mk[4];
            #pragma unroll
            for (int s = 0; s < 4; ++s) mk[s] = __shfl_xor((int)keys[nf][s], off);
            #pragma unroll
            for (int s = 0; s < 4; ++s) insk4(mk[s], keys[nf]);
        }
    }

    // block-level merge in LDS (query buffer dead now): slot (pr, q), 4 pairs x 128 q
    __syncthreads();
    if (kg == 0) {
        #pragma unroll
        for (int nf = 0; nf < 4; ++nf) {
            int q = h * 64 + nf * 16 + lr;
            uint4 v;
            v.x = keys[nf][0]; v.y = keys[nf][1]; v.z = keys[nf][2]; v.w = keys[nf][3];
            *(uint4*)(Bs + ((size_t)pr * 128 + q) * 16) = v;
        }
    }
    __syncthreads();
    if (tid < BQ) {
        int q = tid;
        unsigned V[4] = {0u, 0u, 0u, 0u};
        #pragma unroll
        for (int w = 0; w < 4; ++w) {
            uint4 kk = *(const uint4*)(Bs + ((size_t)w * 128 + q) * 16);
            insk4(kk.x, V); insk4(kk.y, V); insk4(kk.z, V); insk4(kk.w, V);
        }
        uint4 o; o.x = V[0]; o.y = V[1]; o.z = V[2]; o.w = V[3];
        *(uint4*)(pk + (size_t)q * NB4 + (size_t)blockIdx.x * 4) = o;
    }
}

// ---------------- kernel 3: reduce keys -> top-8 -> exact fp32 rescore -> weights ----
__global__ __launch_bounds__(256)
void reduce_rescore(const unsigned* __restrict__ pk, int nb4,
                    const float* __restrict__ ihat, const float* __restrict__ img, int N,
                    float* __restrict__ swo, int* __restrict__ sidxo,
                    int* __restrict__ valido)
{
    __shared__ unsigned lk[256][8];
    __shared__ float sv[8];
    __shared__ int   si[8];
    const int r = blockIdx.x, tid = threadIdx.x;

    unsigned K[8];
    #pragma unroll
    for (int k = 0; k < 8; ++k) K[k] = 0u;
    const unsigned* prow = pk + (size_t)r * nb4;
    for (int j = tid; j < nb4; j += 256) insk8(prow[j], K);
    #pragma unroll
    for (int k = 0; k < 8; ++k) lk[tid][k] = K[k];
    __syncthreads();
    if (tid < 16) {
        for (int o = 1; o < 16; ++o) {
            int t2 = tid + o * 16;
            #pragma unroll
            for (int s = 0; s < 8; ++s) insk8(lk[t2][s], K);
        }
        #pragma unroll
        for (int k = 0; k < 8; ++k) lk[tid][k] = K[k];
    }
    __syncthreads();
    if (tid == 0) {
        for (int o = 1; o < 16; ++o)
            #pragma unroll
            for (int s = 0; s < 8; ++s) insk8(lk[o][s], K);
        #pragma unroll
        for (int k = 0; k < 8; ++k) {
            int idx = (int)((K[k] & IDXM) ^ IDXM);
            si[k] = (K[k] != 0u && idx < N) ? idx : -1;
        }
    }
    __syncthreads();

    // exact fp32 rescore of the 8 candidates (32 lanes each)
    {
        const int k = tid >> 5, l = tid & 31;
        int idx = si[k];
        float dot = 0.f, ssq = 0.f;
        if (idx >= 0) {
            const float* a = ihat + (size_t)r * D + l * 16;
            const float* b = img + (size_t)idx * D + l * 16;
            #pragma unroll
            for (int j = 0; j < 4; ++j) {
                float4 va = *(const float4*)(a + j*4);
                float4 vb = *(const float4*)(b + j*4);
                dot += va.x*vb.x + va.y*vb.y + va.z*vb.z + va.w*vb.w;
                ssq += vb.x*vb.x + vb.y*vb.y + vb.z*vb.z + vb.w*vb.w;
            }
        }
        #pragma unroll
        for (int o = 16; o > 0; o >>= 1) { dot += __shfl_xor(dot, o); ssq += __shfl_xor(ssq, o); }
        if (l == 0) sv[k] = (idx >= 0 && ssq > 0.f) ? dot * rsqrtf(ssq) : -1e30f;
    }
    __syncthreads();

    if (tid == 0) {
        float Vt[4]; int Ct[4];
        #pragma unroll
        for (int k = 0; k < 4; ++k) { Vt[k] = -1e30f; Ct[k] = SENT; }
        #pragma unroll
        for (int k = 0; k < 8; ++k)
            if (si[k] >= 0) insK<4>(sv[k], si[k], Vt, Ct);
        float lg[4]; int vd[3];
        lg[0] = SSCALE;
        #pragma unroll
        for (int k = 0; k < 3; ++k) {
            vd[k] = (Vt[k+1] > THR) ? 1 : 0;
            lg[k+1] = vd[k] ? SSCALE * Vt[k+1] : -1e30f;
        }
        float m = fmaxf(fmaxf(lg[0], lg[1]), fmaxf(lg[2], lg[3]));
        float e0 = expf(lg[0]-m), e1 = expf(lg[1]-m), e2 = expf(lg[2]-m), e3 = expf(lg[3]-m);
        float sum = e0 + e1 + e2 + e3;
        float ee[3] = {e1, e2, e3};
        #pragma unroll
        for (int k = 0; k < 3; ++k) {
            float w = 1.0f - ee[k] / sum;
            swo[r*3+k]    = vd[k] ? w : 0.0f;
            sidxo[r*3+k]  = vd[k] ? Ct[k+1] : 0;
            valido[r*3+k] = vd[k];
        }
    }
}

// ---------------- kernel 4: assemble output (1536 x 512 fp32) ----------------
__global__ void assemble_kernel(const float* __restrict__ i_feats, const float* __restrict__ t_feats,
                                const float* __restrict__ img, const float* __restrict__ txt,
                                const float* __restrict__ sw, const int* __restrict__ sidx,
                                const int* __restrict__ valid, float* __restrict__ out)
{
    const int r = blockIdx.x;      // 0..1535
    const int t = threadIdx.x;     // 0..127
    float4* orow = (float4*)(out + (size_t)r * D);
    if (r < 128) {
        orow[t] = ((const float4*)(i_feats + (size_t)r * D))[t];
    } else if (r < 512) {
        int s = r - 128;
        float4 v = make_float4(0.f,0.f,0.f,0.f);
        if (valid[s]) v = ((const float4*)(img + (size_t)sidx[s] * D))[t];
        orow[t] = v;
    } else if (r < 640) {
        orow[t] = ((const float4*)(t_feats + (size_t)(r - 512) * D))[t];
    } else if (r < 1024) {
        int s = r - 640;
        float4 v = make_float4(0.f,0.f,0.f,0.f);
        if (valid[s]) v = ((const float4*)(txt + (size_t)sidx[s] * D))[t];
        orow[t] = v;
    } else {
        int li = r - 1024;
        float o[4];
        int j0 = t * 4;
        if (li < 128) {
            #pragma unroll
            for (int u = 0; u < 4; ++u) {
                int j = j0 + u;
                if (j < 128) o[u] = (j == li) ? 1.0f : 0.0f;
                else {
                    int s = j - 128;
                    o[u] = (s / 3 == li) ? sw[li*3 + (s % 3)] : 0.0f;
                }
            }
        } else {
            int i2 = li - 128;
            int b = i2 / 3;
            int vi = valid[i2];
            #pragma unroll
            for (int u = 0; u < 4; ++u) {
                int j = j0 + u;
                float val;
                if (j < 128) val = (vi && j == b) ? 1.0f : 0.0f;
                else {
                    int s2 = j - 128;
                    int vj = valid[s2];
                    int b2 = s2 / 3;
                    if (vi && vj)        val = (b == b2) ? 1.0f : 0.0f;
                    else if (!vi && !vj) val = (i2 == s2) ? 1.0f : 0.0f;
                    else                 val = 0.0f;
                }
                o[u] = val;
            }
        }
        orow[t] = make_float4(o[0], o[1], o[2], o[3]);
    }
}

extern "C" void kernel_launch(void* const* d_in, const int* in_sizes, int n_in,
                              void* d_out, int out_size, void* d_ws, size_t ws_size,
                              hipStream_t stream) {
    const float* i_feats = (const float*)d_in[0];
    const float* t_feats = (const float*)d_in[1];
    const float* img     = (const float*)d_in[2];
    const float* txt     = (const float*)d_in[3];
    float* out = (float*)d_out;

    const int N      = in_sizes[2] / D;        // 200000
    const int ntiles = (N + 15) / 16;          // 12500
    const int nit    = (ntiles + NSTR - 1) / NSTR;   // 13

    char* ws = (char*)d_ws;
    size_t off = 0;
    float*    ihat = (float*)(ws + off);    off += (size_t)BQ * D * 4;    // 256 KB
    uint4*    apre = (uint4*)(ws + off);    off += (size_t)BQ * D * 2;    // 128 KB
    unsigned* pk   = (unsigned*)(ws + off); off += (size_t)BQ * NB4 * 4;  // 512 KB
    float*    swv  = (float*)(ws + off);    off += BQ * 4 * 4;
    int*      sidx = (int*)(ws + off);      off += BQ * 4 * 4;
    int*      vld  = (int*)(ws + off);      off += BQ * 4 * 4;

    prep_kernel<<<BQ, 64, 0, stream>>>(i_feats, ihat, apre);
    sim_topk<<<NBLK, 512, 131072, stream>>>(apre, img, N, ntiles, nit, pk);
    reduce_rescore<<<BQ, 256, 0, stream>>>(pk, NB4, ihat, img, N, swv, sidx, vld);
    assemble_kernel<<<3 * (BQ + BQ * KK), 128, 0, stream>>>(i_feats, t_feats, img, txt,
                                                            swv, sidx, vld, out);
}